// Round 1
// 72.680 us; speedup vs baseline: 1.0887x; 1.0887x over previous
//
#include <hip/hip_runtime.h>
#include <math.h>

// Tropical min-max matmul: out[b,o] = min_i max(x[b,i], w[i,o])
// B=1024, I=512, O=512, fp32.
//
// Round 16: EXACT sorted early-exit algorithm (replaces brute force).
//  - Per b-row: sort x[b,:] ascending (bitonic, LDS, 45 substages).
//    Scanning i in ascending-x order, once x_(j) >= best for every
//    tracked output, all future terms max(x_(j'),w) >= x_(j') >= best:
//    break. Bit-exact for ALL inputs; worst case = full scan.
//  - Uniform data: wave (128 cols) converges in ~50-60 of 512 steps.
//  - 1024 blocks x 256 thr = 4 blocks/CU (entire grid resident),
//    4 waves/SIMD. Block = one b-row; wave = 128-col slice; 2 cols/lane.
//  - Scan: uniform LDS broadcast of sorted (val,idx) chunks, gathered
//    w-row float2 loads (512 B/wave contiguous, w is L2-resident),
//    min3-fused updates, one __all vote per 4-step chunk, ping-pong
//    chunk prefetch. No barriers, no cross-wave combine.

__global__ __launch_bounds__(256, 4) void minmax_sorted(
    const float* __restrict__ x,    // [1024, 512]
    const float* __restrict__ w,    // [512, 512]
    float* __restrict__ out)        // [1024, 512]
{
    __shared__ __align__(16) float sv[512];   // sorted x values
    __shared__ __align__(16) int   si[512];   // permutation indices

    const int t = threadIdx.x;      // 0..255
    const int b = blockIdx.x;       // row

    // ---- load row b as (val, idx) pairs ----
    {
        const float2 v = *(const float2*)(x + (size_t)b * 512 + t * 2);
        sv[t * 2]     = v.x;  si[t * 2]     = t * 2;
        sv[t * 2 + 1] = v.y;  si[t * 2 + 1] = t * 2 + 1;
    }
    __syncthreads();

    // ---- bitonic sort ascending by value (idx rides along) ----
    // Each thread owns pair (i, i|j); pairs partition [0,512): no
    // intra-substage hazard, one barrier per substage. <=2-way LDS
    // bank aliasing (free on CDNA4).
    for (int k = 2; k <= 512; k <<= 1) {
        for (int j = k >> 1; j > 0; j >>= 1) {
            const int i = ((t & ~(j - 1)) << 1) | (t & (j - 1));
            const int l = i | j;
            const bool up = ((i & k) == 0);
            const float a = sv[i], c = sv[l];
            const bool sw = up ? (a > c) : (a < c);
            if (sw) {
                const int ia = si[i], ic = si[l];
                sv[i] = c;  sv[l] = a;
                si[i] = ic; si[l] = ia;
            }
            __syncthreads();
        }
    }

    // ---- early-exit scan: wave = 128-col slice, 2 cols per lane ----
    const int wid  = t >> 6;                 // 0..3
    const int lane = t & 63;
    const int o    = wid * 128 + lane * 2;
    const float* wp = w + o;

    float2 acc = make_float2(INFINITY, INFINITY);

#define LDCHUNK(J, XS, R0, R1, R2, R3) do {                     \
        XS = *(const float4*)(&sv[(J)]);                        \
        const int4 ix_ = *(const int4*)(&si[(J)]);              \
        R0 = *(const float2*)(wp + (ix_.x << 9));               \
        R1 = *(const float2*)(wp + (ix_.y << 9));               \
        R2 = *(const float2*)(wp + (ix_.z << 9));               \
        R3 = *(const float2*)(wp + (ix_.w << 9));               \
    } while (0)

#define PROCESS(XS, R0, R1, R2, R3) do {                        \
        const float t0 = fmaxf(XS.x, R0.x);                     \
        const float t1 = fmaxf(XS.y, R1.x);                     \
        const float t2 = fmaxf(XS.z, R2.x);                     \
        const float t3 = fmaxf(XS.w, R3.x);                     \
        acc.x = fminf(fminf(acc.x, t0), t1);  /* v_min3 */      \
        acc.x = fminf(fminf(acc.x, t2), t3);                    \
        const float u0 = fmaxf(XS.x, R0.y);                     \
        const float u1 = fmaxf(XS.y, R1.y);                     \
        const float u2 = fmaxf(XS.z, R2.y);                     \
        const float u3 = fmaxf(XS.w, R3.y);                     \
        acc.y = fminf(fminf(acc.y, u0), u1);                    \
        acc.y = fminf(fminf(acc.y, u2), u3);                    \
    } while (0)

    float4 xsA, xsB;
    float2 a0, a1, a2, a3, b0, b1, b2, b3;
    LDCHUNK(0, xsA, a0, a1, a2, a3);
    LDCHUNK(4, xsB, b0, b1, b2, b3);

    int j = 0;
    for (;;) {
        // chunk j is in A
        PROCESS(xsA, a0, a1, a2, a3);
        if (__all(xsA.w >= fmaxf(acc.x, acc.y))) break;
        j += 4; if (j >= 512) break;
        { int jn = j + 4; if (jn > 508) jn = 508;
          LDCHUNK(jn, xsA, a0, a1, a2, a3); }     // prefetch chunk j+4
        // chunk j is in B
        PROCESS(xsB, b0, b1, b2, b3);
        if (__all(xsB.w >= fmaxf(acc.x, acc.y))) break;
        j += 4; if (j >= 512) break;
        { int jn = j + 4; if (jn > 508) jn = 508;
          LDCHUNK(jn, xsB, b0, b1, b2, b3); }
    }

#undef LDCHUNK
#undef PROCESS

    *(float2*)(out + (size_t)b * 512 + o) = acc;
}

extern "C" void kernel_launch(void* const* d_in, const int* in_sizes, int n_in,
                              void* d_out, int out_size, void* d_ws, size_t ws_size,
                              hipStream_t stream) {
    const float* x = (const float*)d_in[0];   // [1024, 512]
    const float* w = (const float*)d_in[1];   // [512, 512]
    float* out = (float*)d_out;               // [1024, 512]

    minmax_sorted<<<dim3(1024), 256, 0, stream>>>(x, w, out);
}